// Round 11
// baseline (147.621 us; speedup 1.0000x reference)
//
#include <hip/hip_runtime.h>
#include <hip/hip_bf16.h>

typedef __bf16 v8bf __attribute__((ext_vector_type(8)));
typedef float f32x4 __attribute__((ext_vector_type(4)));

static __device__ __forceinline__ unsigned short f2b(float f){
  union { float f; unsigned int u; } c; c.f = f;
  return (unsigned short)((c.u + 0x7FFFu + ((c.u >> 16) & 1u)) >> 16);
}
static __device__ __forceinline__ float b2f(unsigned int h){
  union { unsigned int u; float f; } c; c.u = h << 16; return c.f;
}

static __device__ __forceinline__ void gld_lds16(const void* g, void* l){
  __builtin_amdgcn_global_load_lds(
      (const __attribute__((address_space(1))) unsigned int*)g,
      (__attribute__((address_space(3))) unsigned int*)l, 16, 0, 0);
}

#define FENCE __builtin_amdgcn_sched_barrier(0)

// ---------------------------------------------------------------------------
// m201-template port (scores): C(256x256) = A(256xK)*B(256xK)^T, bf16, BK=64.
// 512 thr = 8 waves (2Mx4N), per-wave 128x64 = acc[8][4].
// LDS 160KB: A 2 slots x 32KB @0; B 3 slots x 32KB @65536.
// 8 phases / 2 K-tiles; phase p: {12 ds_reads (one 64x32 C-quadrant's frags) |
// stage 1 half-tile (2 gloads) | barrier | lgkmcnt(0) | 16 MFMA (setprio) |
// [vmcnt(4) @p3,p7] | barrier}.
// Stage order (iter computes kt,kt+1): p0,p1: A(kt+1)h0,h1 -> Aslot1;
// p2,p3: B(kt+2) -> Bslot (kt+2)%3 (freed: held kt-1); p4,p5: A(kt+2) -> Aslot0
// (freed @p3); p6,p7: B(kt+3) -> Bslot kt%3 (freed @p3). Min staging->use gap
// = 3 phases. vmcnt(4)@p3: 4 newest = B(kt+2) -> A(kt+1),B(kt+1) resident.
// vmcnt(4)@p7: 4 newest = B(kt+3) -> A(kt+2),B(kt+2) resident. NT even.
// Swizzle: 16B-chunk ^= (row&7) on stage-source and ds_read (0 conflicts).
// ---------------------------------------------------------------------------
static __device__ __forceinline__ void gemm8p(
    const unsigned short* __restrict__ A, int lda,
    const unsigned short* __restrict__ B, int ldb,
    int NT, unsigned short* smem, f32x4 acc[8][4])
{
  const int tid  = threadIdx.x;
  const int lane = tid & 63;
  const int w    = tid >> 6;
  const int wr   = w >> 2, wc = w & 3;
  const int lr   = lane & 15, lg = lane >> 4;
  char* sm = (char*)smem;

  #pragma unroll
  for (int m=0;m<8;++m)
    #pragma unroll
    for (int n=0;n<4;++n)
      acc[m][n] = (f32x4){0.f,0.f,0.f,0.f};

  const int rloc = tid >> 3;
  const int scol = ((tid & 7) ^ ((tid >> 3) & 7)) << 3;
  const unsigned short* Ab0 = A + (size_t)rloc*lda + scol;
  const unsigned short* Bb0 = B + (size_t)rloc*ldb + scol;

  // stage one half-tile (128 rows) = 2 gloads (issues of 64 rows)
  auto stA2 = [&](int slot, int h, int kE){
    gld_lds16(Ab0 + (size_t)(h*128)*lda + kE,      sm + slot*32768 + h*16384 + w*1024);
    gld_lds16(Ab0 + (size_t)(h*128+64)*lda + kE,   sm + slot*32768 + h*16384 + 8192 + w*1024);
  };
  auto stB2 = [&](int slot, int h, int kE){
    gld_lds16(Bb0 + (size_t)(h*128)*ldb + kE,      sm + 65536 + slot*32768 + h*16384 + w*1024);
    gld_lds16(Bb0 + (size_t)(h*128+64)*ldb + kE,   sm + 65536 + slot*32768 + h*16384 + 8192 + w*1024);
  };

  const int ce0 = (((lg*8))      ^ ((lr&7)<<3)) * 2;
  const int ce1 = (((32 + lg*8)) ^ ((lr&7)<<3)) * 2;

  // prologue: A(0)->slot0, B(0)->Bslot0, B(1)->Bslot1
  stA2(0,0,0); stA2(0,1,0);
  stB2(0,0,0); stB2(0,1,0);
  stB2(1,0,64); stB2(1,1,64);
  asm volatile("s_waitcnt vmcnt(4)" ::: "memory");   // B(1) may fly
  __builtin_amdgcn_s_barrier();

  int b0 = 0;                                        // Bslot of kt
  for (int kt = 0; kt < NT; kt += 2) {
    const int b1 = (b0+1==3)?0:b0+1;                 // Bslot of kt+1
    const int b2 = (b1+1==3)?0:b1+1;                 // Bslot of kt+2 (free)
    const int kA1 = (kt+1 < NT ? kt+1 : NT-1)*64;
    const int k2  = (kt+2 < NT ? kt+2 : NT-1)*64;
    const int k3  = (kt+3 < NT ? kt+3 : NT-1)*64;

    #pragma unroll
    for (int tp=0; tp<2; ++tp) {
      const int rdB = (tp==0) ? b0 : b1;
      #pragma unroll
      for (int q=0; q<4; ++q) {
        const int mh = q>>1, nh = q&1;
        // 12 ds_reads: this quadrant's A (4x2) + B (2x2) frags
        v8bf a[4][2], b[2][2];
        char* Ab = sm + tp*32768;
        #pragma unroll
        for (int mm=0;mm<4;++mm){
          char* rp = Ab + (wr*128 + mh*64 + mm*16 + lr)*128;
          a[mm][0] = *(const v8bf*)(rp + ce0);
          a[mm][1] = *(const v8bf*)(rp + ce1);
        }
        char* Bb = sm + 65536 + rdB*32768;
        #pragma unroll
        for (int nn=0;nn<2;++nn){
          char* rp = Bb + (wc*64 + nh*32 + nn*16 + lr)*128;
          b[nn][0] = *(const v8bf*)(rp + ce0);
          b[nn][1] = *(const v8bf*)(rp + ce1);
        }
        // stage one half-tile per phase (p = tp*4+q)
        if      (tp==0 && q==0) stA2(1, 0, kA1);
        else if (tp==0 && q==1) stA2(1, 1, kA1);
        else if (tp==0 && q==2) stB2(b2, 0, k2);
        else if (tp==0 && q==3) stB2(b2, 1, k2);
        else if (tp==1 && q==0) stA2(0, 0, k2);
        else if (tp==1 && q==1) stA2(0, 1, k2);
        else if (tp==1 && q==2) stB2(b0, 0, k3);
        else                    stB2(b0, 1, k3);

        __builtin_amdgcn_s_barrier();
        asm volatile("s_waitcnt lgkmcnt(0)" ::: "memory");
        FENCE;
        __builtin_amdgcn_s_setprio(1);
        #pragma unroll
        for (int mm=0;mm<4;++mm)
          #pragma unroll
          for (int nn=0;nn<2;++nn){
            acc[mh*4+mm][nh*2+nn] = __builtin_amdgcn_mfma_f32_16x16x32_bf16(a[mm][0], b[nn][0], acc[mh*4+mm][nh*2+nn], 0,0,0);
            acc[mh*4+mm][nh*2+nn] = __builtin_amdgcn_mfma_f32_16x16x32_bf16(a[mm][1], b[nn][1], acc[mh*4+mm][nh*2+nn], 0,0,0);
          }
        __builtin_amdgcn_s_setprio(0);
        if (q==3) asm volatile("s_waitcnt vmcnt(4)" ::: "memory");
        __builtin_amdgcn_s_barrier();
      }
    }
    b0 = b2;   // (b0+2)%3
  }
}

// ---------------------------------------------------------------------------
// TLP core (qkv): C(128x192) = A(128xK)*B(192xK)^T. 80KB LDS -> 2 blocks/CU.
// Proven 65us/890TF (r9/r10).
// ---------------------------------------------------------------------------
static __device__ __forceinline__ void gemm128(
    const unsigned short* __restrict__ A, int lda,
    const unsigned short* __restrict__ B, int ldb,
    int NT, unsigned short* smem, f32x4 acc[4][3])
{
  const int tid  = threadIdx.x;
  const int lane = tid & 63;
  const int w    = tid >> 6;
  const int wr   = w >> 2, wc = w & 3;
  const int lr   = lane & 15, lg = lane >> 4;
  char* sm = (char*)smem;

  #pragma unroll
  for (int m=0;m<4;++m)
    #pragma unroll
    for (int n=0;n<3;++n)
      acc[m][n] = (f32x4){0.f,0.f,0.f,0.f};

  const int rloc = tid >> 3;
  const int scol = ((tid & 7) ^ ((tid >> 3) & 7)) << 3;
  const unsigned short* Ab0 = A + (size_t)rloc*lda + scol;
  const unsigned short* Bb0 = B + (size_t)rloc*ldb + scol;

  auto stA = [&](int d, int i, int kE){
    gld_lds16(Ab0 + (size_t)(i*64)*lda + kE, sm + d*16384 + i*8192 + w*1024);
  };
  auto stB = [&](int d, int i, int kE){
    gld_lds16(Bb0 + (size_t)(i*64)*ldb + kE, sm + 32768 + d*24576 + i*8192 + w*1024);
  };

  const int ce0 = (((lg*8))      ^ ((lr&7)<<3)) * 2;
  const int ce1 = (((32 + lg*8)) ^ ((lr&7)<<3)) * 2;

  stA(0,0,0); stA(0,1,0);
  stB(0,0,0); stB(0,1,0); stB(0,2,0);
  asm volatile("s_waitcnt vmcnt(0)" ::: "memory");
  __builtin_amdgcn_s_barrier();

  for (int kt = 0; kt < NT; ++kt) {
    const int d  = kt & 1;
    const int kN = (kt+1 < NT ? kt+1 : NT-1)*64;
    stA(d^1,0,kN); stA(d^1,1,kN);
    stB(d^1,0,kN); stB(d^1,1,kN); stB(d^1,2,kN);
    v8bf a[4][2], b[3][2];
    char* Abase = sm + d*16384;
    char* Bbase = sm + 32768 + d*24576;
    #pragma unroll
    for (int m=0;m<4;++m){
      char* rp = Abase + (wr*64 + m*16 + lr)*128;
      a[m][0] = *(const v8bf*)(rp + ce0);
      a[m][1] = *(const v8bf*)(rp + ce1);
    }
    #pragma unroll
    for (int n=0;n<3;++n){
      char* rp = Bbase + (wc*48 + n*16 + lr)*128;
      b[n][0] = *(const v8bf*)(rp + ce0);
      b[n][1] = *(const v8bf*)(rp + ce1);
    }
    FENCE; asm volatile("s_waitcnt lgkmcnt(0)" ::: "memory"); FENCE;
    __builtin_amdgcn_s_setprio(1);
    #pragma unroll
    for (int m=0;m<4;++m)
      #pragma unroll
      for (int n=0;n<3;++n){
        acc[m][n] = __builtin_amdgcn_mfma_f32_16x16x32_bf16(a[m][0], b[n][0], acc[m][n], 0,0,0);
        acc[m][n] = __builtin_amdgcn_mfma_f32_16x16x32_bf16(a[m][1], b[n][1], acc[m][n], 0,0,0);
      }
    __builtin_amdgcn_s_setprio(0);
    asm volatile("s_waitcnt vmcnt(0)" ::: "memory");
    __builtin_amdgcn_s_barrier();
  }
}

// ---------------------------------------------------------------------------
// Pipelined 256x192 core (pv): NW=3, DEEP A-prefetch. r8/r10-proven.
// ---------------------------------------------------------------------------
static __device__ __forceinline__ void gemmpv(
    const unsigned short* __restrict__ A, int lda,
    const unsigned short* __restrict__ B, int ldb,
    int NT, unsigned short* smem, f32x4 acc[8][3])
{
  const int tid  = threadIdx.x;
  const int lane = tid & 63;
  const int w    = tid >> 6;
  const int wr   = w >> 2, wc = w & 3;
  const int lr   = lane & 15, lg = lane >> 4;
  char* sm = (char*)smem;
  constexpr int BBASE = 3 * 32768;
  constexpr int BBUF  = 3 * 8192;

  #pragma unroll
  for (int m=0;m<8;++m)
    #pragma unroll
    for (int n=0;n<3;++n)
      acc[m][n] = (f32x4){0.f,0.f,0.f,0.f};

  const int rloc = tid >> 3;
  const int scol = ((tid & 7) ^ ((tid >> 3) & 7)) << 3;
  const unsigned short* Ab0 = A + (size_t)rloc*lda + scol;
  const unsigned short* Bb0 = B + (size_t)rloc*ldb + scol;

  auto stA = [&](int ab, int i, int kE){
    gld_lds16(Ab0 + (size_t)(i*64)*lda + kE, sm + ab*32768 + i*8192 + w*1024);
  };
  auto stB = [&](int db, int i, int kE){
    gld_lds16(Bb0 + (size_t)(i*64)*ldb + kE, sm + BBASE + db*BBUF + i*8192 + w*1024);
  };

  const int ce0 = (((lg*8))      ^ ((lr&7)<<3)) * 2;
  const int ce1 = (((32 + lg*8)) ^ ((lr&7)<<3)) * 2;

  v8bf bX[3][2], bY[3][2], af0[2][2], af1[2][2];

  auto rdA = [&](v8bf (&dst)[2][2], char* base, int qq){
    #pragma unroll
    for (int mm=0;mm<2;++mm){
      char* rp = base + ((qq*2+mm)*16+lr)*128;
      dst[mm][0] = *(const v8bf*)(rp + ce0);
      dst[mm][1] = *(const v8bf*)(rp + ce1);
    }
  };
  auto rdB = [&](v8bf (&dst)[3][2], char* base){
    #pragma unroll
    for (int n=0;n<3;++n){
      char* rp = base + (n*16+lr)*128;
      dst[n][0] = *(const v8bf*)(rp + ce0);
      dst[n][1] = *(const v8bf*)(rp + ce1);
    }
  };
  auto domfma = [&](v8bf (&a)[2][2], v8bf (&bb)[3][2], int qq){
    __builtin_amdgcn_s_setprio(1);
    #pragma unroll
    for (int mm=0;mm<2;++mm)
      #pragma unroll
      for (int n=0;n<3;++n){
        acc[qq*2+mm][n] = __builtin_amdgcn_mfma_f32_16x16x32_bf16(a[mm][0], bb[n][0], acc[qq*2+mm][n], 0,0,0);
        acc[qq*2+mm][n] = __builtin_amdgcn_mfma_f32_16x16x32_bf16(a[mm][1], bb[n][1], acc[qq*2+mm][n], 0,0,0);
      }
    __builtin_amdgcn_s_setprio(0);
  };

  auto ktile = [&](int kt, int ar, int an, int as,
                   v8bf (&bc)[3][2], v8bf (&bn)[3][2]){
    char* Ab = sm + ar*32768 + wr*16384;
    char* An = sm + an*32768 + wr*16384;
    char* Bn = sm + BBASE + ((kt+1)&1)*BBUF + wc*(3*2048);
    const int kA = (kt+2 < NT ? kt+2 : NT-1)*64;
    const int kB = (kt+2 < NT ? kt+2 : NT-1)*64;
    const int db = kt & 1;

    stA(as,0,kA); stA(as,1,kA);
    rdA(af1, Ab, 1);
    FENCE; asm volatile("s_waitcnt lgkmcnt(4)" ::: "memory"); FENCE;
    domfma(af0, bc, 0);
    __builtin_amdgcn_s_barrier();

    stA(as,2,kA); stA(as,3,kA);
    rdA(af0, Ab, 2);
    FENCE; asm volatile("s_waitcnt lgkmcnt(4)" ::: "memory"); FENCE;
    domfma(af1, bc, 1);
    __builtin_amdgcn_s_barrier();

    stB(db,0,kB); stB(db,1,kB);
    rdA(af1, Ab, 3);
    FENCE; asm volatile("s_waitcnt lgkmcnt(4)" ::: "memory"); FENCE;
    domfma(af0, bc, 2);
    asm volatile("s_waitcnt vmcnt(6)" ::: "memory");
    __builtin_amdgcn_s_barrier();

    stB(db,2,kB);
    rdA(af0, An, 0);
    rdB(bn, Bn);
    FENCE; asm volatile("s_waitcnt lgkmcnt(10)" ::: "memory"); FENCE;
    domfma(af1, bc, 3);
    __builtin_amdgcn_s_barrier();
  };

  #pragma unroll
  for (int i=0;i<4;++i) stA(0,i,0);
  #pragma unroll
  for (int i=0;i<3;++i) stB(0,i,0);
  #pragma unroll
  for (int i=0;i<4;++i) stA(1,i,64);
  #pragma unroll
  for (int i=0;i<3;++i) stB(1,i,64);
  asm volatile("s_waitcnt vmcnt(7)" ::: "memory");
  __builtin_amdgcn_s_barrier();
  rdB(bX, sm + BBASE + wc*(3*2048));
  rdA(af0, sm + wr*16384, 0);

  int c0 = 0;
  for (int kt = 0; kt < NT; kt += 2) {
    const int c1 = (c0+1==3) ? 0 : c0+1;
    const int c2 = (c1+1==3) ? 0 : c1+1;
    ktile(kt,   c0, c1, c2, bX, bY);
    ktile(kt+1, c1, c2, c0, bY, bX);
    c0 = c2;
  }
}

// ---------------- convert: x, Wq/Wk/Wv f32 -> bf16 -------------------------
__global__ __launch_bounds__(256) void convert_kernel(
    const float* __restrict__ x,
    const float* __restrict__ Wq, const float* __restrict__ Wk,
    const float* __restrict__ Wv,
    unsigned short* __restrict__ Xb, unsigned short* __restrict__ Wb)
{
  const int NX = 3145728;
  const int NW_ = 147456;
  const int total = NX + 3*NW_;
  for (int i = blockIdx.x*256 + threadIdx.x; i < total; i += gridDim.x*256) {
    const float* src; unsigned short* dst; int off;
    if (i < NX) { src = x; dst = Xb; off = i; }
    else {
      int j = i - NX; int z = j / NW_; off = j - z*NW_;
      src = (z==0) ? Wq : ((z==1) ? Wk : Wv);
      dst = Wb + (size_t)z*589824;
    }
    float4 v = reinterpret_cast<const float4*>(src)[off];
    ushort4 h; h.x=f2b(v.x); h.y=f2b(v.y); h.z=f2b(v.z); h.w=f2b(v.w);
    reinterpret_cast<ushort4*>(dst)[off] = h;
  }
}

// ---------------- QKV: one GEMM [16384x768] x [2304x768]^T, tile 128x192 ---
__global__ __launch_bounds__(512, 4) void qkv_kernel(
    const unsigned short* __restrict__ Xb, const unsigned short* __restrict__ Wb,
    const float* __restrict__ bq, const float* __restrict__ bk,
    const float* __restrict__ bv,
    unsigned short* __restrict__ Qb, unsigned short* __restrict__ Kb,
    unsigned short* __restrict__ Vt)
{
  extern __shared__ unsigned short smem[];
  const int bid = blockIdx.x;
  const int wg  = (bid & 7)*192 + (bid >> 3);
  const int mt  = wg / 12, nt = wg % 12;

  f32x4 acc[4][3];
  gemm128(Xb + (size_t)mt*128*768, 768,
          Wb + (size_t)nt*192*768, 768, 12, smem, acc);

  const int tid = threadIdx.x, lane = tid & 63, w = tid >> 6;
  const int wr = w >> 2, wc = w & 3, lr = lane & 15, lg = lane >> 4;
  const int z = nt >> 2;
  const float* bias = (z==0) ? bq : ((z==1) ? bk : bv);
  const int colbase = (nt & 3)*192 + wc*48;

  if (z < 2) {
    unsigned short* dst = (z==0) ? Qb : Kb;
    #pragma unroll
    for (int m=0;m<4;++m){
      int row0 = mt*128 + wr*64 + m*16 + lg*4;
      #pragma unroll
      for (int n=0;n<3;++n){
        int col = colbase + n*16 + lr;
        float bb = bias[col];
        #pragma unroll
        for (int r=0;r<4;++r)
          dst[(size_t)(row0+r)*768 + col] = f2b(acc[m][n][r] + bb);
      }
    }
  } else {
    const int batch = mt >> 3;
    const int ebase = (mt & 7)*128;
    unsigned short* dst = Vt + (size_t)batch*786432;
    #pragma unroll
    for (int m=0;m<4;++m){
      int e0 = ebase + wr*64 + m*16 + lg*4;
      #pragma unroll
      for (int n=0;n<3;++n){
        int col = colbase + n*16 + lr;
        float bb = bias[col];
        ushort4 h;
        h.x = f2b(acc[m][n][0] + bb);
        h.y = f2b(acc[m][n][1] + bb);
        h.z = f2b(acc[m][n][2] + bb);
        h.w = f2b(acc[m][n][3] + bb);
        *reinterpret_cast<ushort4*>(dst + (size_t)col*1024 + e0) = h;
      }
    }
  }
}

// ---------------- scores: E = exp((Q K^T) * 768^-0.5), bf16 (m201 core) ----
__global__ __launch_bounds__(512, 2) void scores_kernel(
    const unsigned short* __restrict__ Qb,
    const unsigned short* __restrict__ Kb,
    unsigned short* __restrict__ Eb)
{
  extern __shared__ unsigned short smem[];
  const int lid = blockIdx.x;
  const int seq = lid >> 3;
  const int b   = (lid & 7)*2 + (seq >> 4);
  const int t   = seq & 15;
  const int mt  = t >> 2, nt = t & 3;

  f32x4 acc[8][4];
  gemm8p(Qb + (size_t)b*786432 + (size_t)mt*256*768, 768,
         Kb + (size_t)b*786432 + (size_t)nt*256*768, 768,
         12, smem, acc);

  const float scale = 0.03608439182435161f; // 768^-0.5
  const int tid = threadIdx.x, lane = tid & 63, w = tid >> 6;
  const int wr = w >> 2, wc = w & 3, lr = lane & 15, lg = lane >> 4;
  unsigned short* dst = Eb + (size_t)b*1048576;
  #pragma unroll
  for (int m=0;m<8;++m){
    int row0 = mt*256 + wr*128 + m*16 + lg*4;
    #pragma unroll
    for (int n=0;n<4;++n){
      int col = nt*256 + wc*64 + n*16 + lr;
      #pragma unroll
      for (int r=0;r<4;++r)
        dst[(size_t)(row0+r)*1024 + col] = f2b(__expf(acc[m][n][r] * scale));
    }
  }
}

// ---------------- rowsum: D[b*1024+c] = sum_e E[b][c][e] -------------------
__global__ __launch_bounds__(256) void rowsum_kernel(
    const unsigned short* __restrict__ E, float* __restrict__ D)
{
  int row  = blockIdx.x*4 + (threadIdx.x >> 6);
  int lane = threadIdx.x & 63;
  const unsigned short* p = E + (size_t)row*1024 + lane*16;
  uint4 v0 = *reinterpret_cast<const uint4*>(p);
  uint4 v1 = *reinterpret_cast<const uint4*>(p + 8);
  unsigned int uu[8] = {v0.x, v0.y, v0.z, v0.w, v1.x, v1.y, v1.z, v1.w};
  float s = 0.f;
  #pragma unroll
  for (int i=0;i<8;++i){ s += b2f(uu[i] & 0xffffu); s += b2f(uu[i] >> 16); }
  #pragma unroll
  for (int off=1; off<64; off<<=1) s += __shfl_xor(s, off, 64);
  if (lane == 0) D[row] = s;
}

// -------- PV: out[b, n*1024+c] = (E V)[c,n]/D[b,c] + x[b, n*1024+c] --------
__global__ __launch_bounds__(512, 2) void pv_kernel(
    const unsigned short* __restrict__ Eb,
    const unsigned short* __restrict__ Vt,
    const float* __restrict__ D,
    const float* __restrict__ x, float* __restrict__ out)
{
  extern __shared__ unsigned short smem[];
  const int lid = blockIdx.x;
  const int seq = lid >> 3;
  const int b   = (lid & 7)*2 + (seq >> 4);
  const int t   = seq & 15;
  const int mt  = t >> 2, nt = t & 3;

  f32x4 acc[8][3];
  gemmpv(Eb + (size_t)b*1048576 + (size_t)mt*256*1024, 1024,
         Vt + (size_t)b*786432  + (size_t)nt*192*1024, 1024,
         16, smem, acc);

  const int tid = threadIdx.x, lane = tid & 63, w = tid >> 6;
  const int wr = w >> 2, wc = w & 3, lr = lane & 15, lg = lane >> 4;
  const float* xb = x   + (size_t)b*786432;
  float*       ob = out + (size_t)b*786432;
  const float* Db = D + b*1024;
  #pragma unroll
  for (int m=0;m<8;++m){
    int c0 = mt*256 + wr*128 + m*16 + lg*4;
    float inv0 = 1.0f / Db[c0+0];
    float inv1 = 1.0f / Db[c0+1];
    float inv2 = 1.0f / Db[c0+2];
    float inv3 = 1.0f / Db[c0+3];
    #pragma unroll
    for (int n=0;n<3;++n){
      int col = nt*192 + wc*48 + n*16 + lr;
      size_t idx = (size_t)col*1024 + c0;
      float4 xv = *reinterpret_cast<const float4*>(xb + idx);
      float4 o;
      o.x = acc[m][n][0]*inv0 + xv.x;
      o.y = acc[m][n][1]*inv1 + xv.y;
      o.z = acc[m][n][2]*inv2 + xv.z;
      o.w = acc[m][n][3]*inv3 + xv.w;
      *reinterpret_cast<float4*>(ob + idx) = o;
    }
  }
}

extern "C" void kernel_launch(void* const* d_in, const int* in_sizes, int n_in,
                              void* d_out, int out_size, void* d_ws, size_t ws_size,
                              hipStream_t stream)
{
  const float* x  = (const float*)d_in[0];
  const float* Wq = (const float*)d_in[1];
  const float* bq = (const float*)d_in[2];
  const float* Wk = (const float*)d_in[3];
  const float* bk = (const float*)d_in[4];
  const float* Wv = (const float*)d_in[5];
  const float* bv = (const float*)d_in[6];
  float* out = (float*)d_out;

  // Workspace (104 MiB, aliased):
  //   [0, 32M)   : Xb (24M) + Wb (3.4M) during convert+qkv; Eb (32M) after
  //   [32M, 56M) : Qb during qkv+scores; D (64KB, dead-Qb reuse) after
  //   [56M, 80M) : Kb   [80M, 104M) : Vt
  char* ws = (char*)d_ws;
  unsigned short* Xb = (unsigned short*)(ws);
  unsigned short* Wb = (unsigned short*)(ws + 25165824);
  unsigned short* Eb = (unsigned short*)(ws);
  unsigned short* Qb = (unsigned short*)(ws + 33554432);
  float*          Dd = (float*)         (ws + 33554432);
  unsigned short* Kb = (unsigned short*)(ws + 58720256);
  unsigned short* Vt = (unsigned short*)(ws + 83886080);

  convert_kernel<<<dim3(2048), dim3(256), 0,      stream>>>(x, Wq, Wk, Wv, Xb, Wb);
  qkv_kernel    <<<dim3(1536), dim3(512), 81920,  stream>>>(Xb, Wb, bq, bk, bv, Qb, Kb, Vt);
  scores_kernel <<<dim3(256),  dim3(512), 163840, stream>>>(Qb, Kb, Eb);
  rowsum_kernel <<<dim3(4096), dim3(256), 0,      stream>>>(Eb, Dd);
  pv_kernel     <<<dim3(256),  dim3(512), 147456, stream>>>(Eb, Vt, Dd, x, out);
}

// Round 12
// 142.985 us; speedup vs baseline: 1.0324x; 1.0324x over previous
//
#include <hip/hip_runtime.h>
#include <hip/hip_bf16.h>

typedef __bf16 v8bf __attribute__((ext_vector_type(8)));
typedef float f32x4 __attribute__((ext_vector_type(4)));

static __device__ __forceinline__ unsigned short f2b(float f){
  union { float f; unsigned int u; } c; c.f = f;
  return (unsigned short)((c.u + 0x7FFFu + ((c.u >> 16) & 1u)) >> 16);
}
static __device__ __forceinline__ float b2f(unsigned int h){
  union { unsigned int u; float f; } c; c.u = h << 16; return c.f;
}

static __device__ __forceinline__ void gld_lds16(const void* g, void* l){
  __builtin_amdgcn_global_load_lds(
      (const __attribute__((address_space(1))) unsigned int*)g,
      (__attribute__((address_space(3))) unsigned int*)l, 16, 0, 0);
}

#define FENCE __builtin_amdgcn_sched_barrier(0)

// ---------------------------------------------------------------------------
// TLP core (qkv): C(128x192) = A(128xK)*B(192xK)^T. 80KB LDS -> 2 blocks/CU.
// Proven 65us/890TF (r9/r10).
// ---------------------------------------------------------------------------
static __device__ __forceinline__ void gemm128(
    const unsigned short* __restrict__ A, int lda,
    const unsigned short* __restrict__ B, int ldb,
    int NT, unsigned short* smem, f32x4 acc[4][3])
{
  const int tid  = threadIdx.x;
  const int lane = tid & 63;
  const int w    = tid >> 6;
  const int wr   = w >> 2, wc = w & 3;
  const int lr   = lane & 15, lg = lane >> 4;
  char* sm = (char*)smem;

  #pragma unroll
  for (int m=0;m<4;++m)
    #pragma unroll
    for (int n=0;n<3;++n)
      acc[m][n] = (f32x4){0.f,0.f,0.f,0.f};

  const int rloc = tid >> 3;
  const int scol = ((tid & 7) ^ ((tid >> 3) & 7)) << 3;
  const unsigned short* Ab0 = A + (size_t)rloc*lda + scol;
  const unsigned short* Bb0 = B + (size_t)rloc*ldb + scol;

  auto stA = [&](int d, int i, int kE){
    gld_lds16(Ab0 + (size_t)(i*64)*lda + kE, sm + d*16384 + i*8192 + w*1024);
  };
  auto stB = [&](int d, int i, int kE){
    gld_lds16(Bb0 + (size_t)(i*64)*ldb + kE, sm + 32768 + d*24576 + i*8192 + w*1024);
  };

  const int ce0 = (((lg*8))      ^ ((lr&7)<<3)) * 2;
  const int ce1 = (((32 + lg*8)) ^ ((lr&7)<<3)) * 2;

  stA(0,0,0); stA(0,1,0);
  stB(0,0,0); stB(0,1,0); stB(0,2,0);
  asm volatile("s_waitcnt vmcnt(0)" ::: "memory");
  __builtin_amdgcn_s_barrier();

  for (int kt = 0; kt < NT; ++kt) {
    const int d  = kt & 1;
    const int kN = (kt+1 < NT ? kt+1 : NT-1)*64;
    stA(d^1,0,kN); stA(d^1,1,kN);
    stB(d^1,0,kN); stB(d^1,1,kN); stB(d^1,2,kN);
    v8bf a[4][2], b[3][2];
    char* Abase = sm + d*16384;
    char* Bbase = sm + 32768 + d*24576;
    #pragma unroll
    for (int m=0;m<4;++m){
      char* rp = Abase + (wr*64 + m*16 + lr)*128;
      a[m][0] = *(const v8bf*)(rp + ce0);
      a[m][1] = *(const v8bf*)(rp + ce1);
    }
    #pragma unroll
    for (int n=0;n<3;++n){
      char* rp = Bbase + (wc*48 + n*16 + lr)*128;
      b[n][0] = *(const v8bf*)(rp + ce0);
      b[n][1] = *(const v8bf*)(rp + ce1);
    }
    FENCE; asm volatile("s_waitcnt lgkmcnt(0)" ::: "memory"); FENCE;
    __builtin_amdgcn_s_setprio(1);
    #pragma unroll
    for (int m=0;m<4;++m)
      #pragma unroll
      for (int n=0;n<3;++n){
        acc[m][n] = __builtin_amdgcn_mfma_f32_16x16x32_bf16(a[m][0], b[n][0], acc[m][n], 0,0,0);
        acc[m][n] = __builtin_amdgcn_mfma_f32_16x16x32_bf16(a[m][1], b[n][1], acc[m][n], 0,0,0);
      }
    __builtin_amdgcn_s_setprio(0);
    asm volatile("s_waitcnt vmcnt(0)" ::: "memory");
    __builtin_amdgcn_s_barrier();
  }
}

// ---------------------------------------------------------------------------
// Pipelined 256xBN core (scores NW=4 DEEP=0, pv NW=3 DEEP=1). r8/r10-proven.
// ---------------------------------------------------------------------------
template<int NW, bool DEEP>
static __device__ __forceinline__ void gemmcore(
    const unsigned short* __restrict__ A, int lda,
    const unsigned short* __restrict__ B, int ldb,
    int NT, unsigned short* smem, f32x4 acc[8][NW])
{
  const int tid  = threadIdx.x;
  const int lane = tid & 63;
  const int w    = tid >> 6;
  const int wr   = w >> 2, wc = w & 3;
  const int lr   = lane & 15, lg = lane >> 4;
  char* sm = (char*)smem;
  constexpr int NAB   = DEEP ? 3 : 2;
  constexpr int BBASE = NAB * 32768;
  constexpr int BBUF  = NW * 8192;

  #pragma unroll
  for (int m=0;m<8;++m)
    #pragma unroll
    for (int n=0;n<NW;++n)
      acc[m][n] = (f32x4){0.f,0.f,0.f,0.f};

  const int rloc = tid >> 3;
  const int scol = ((tid & 7) ^ ((tid >> 3) & 7)) << 3;
  const unsigned short* Ab0 = A + (size_t)rloc*lda + scol;
  const unsigned short* Bb0 = B + (size_t)rloc*ldb + scol;

  auto stA = [&](int ab, int i, int kE){
    gld_lds16(Ab0 + (size_t)(i*64)*lda + kE, sm + ab*32768 + i*8192 + w*1024);
  };
  auto stB = [&](int db, int i, int kE){
    gld_lds16(Bb0 + (size_t)(i*64)*ldb + kE, sm + BBASE + db*BBUF + i*8192 + w*1024);
  };

  const int ce0 = (((lg*8))      ^ ((lr&7)<<3)) * 2;
  const int ce1 = (((32 + lg*8)) ^ ((lr&7)<<3)) * 2;

  v8bf bX[NW][2], bY[NW][2], af0[2][2], af1[2][2];

  auto rdA = [&](v8bf (&dst)[2][2], char* base, int qq){
    #pragma unroll
    for (int mm=0;mm<2;++mm){
      char* rp = base + ((qq*2+mm)*16+lr)*128;
      dst[mm][0] = *(const v8bf*)(rp + ce0);
      dst[mm][1] = *(const v8bf*)(rp + ce1);
    }
  };
  auto rdB = [&](v8bf (&dst)[NW][2], char* base){
    #pragma unroll
    for (int n=0;n<NW;++n){
      char* rp = base + (n*16+lr)*128;
      dst[n][0] = *(const v8bf*)(rp + ce0);
      dst[n][1] = *(const v8bf*)(rp + ce1);
    }
  };
  auto domfma = [&](v8bf (&a)[2][2], v8bf (&bb)[NW][2], int qq){
    __builtin_amdgcn_s_setprio(1);
    #pragma unroll
    for (int mm=0;mm<2;++mm)
      #pragma unroll
      for (int n=0;n<NW;++n){
        acc[qq*2+mm][n] = __builtin_amdgcn_mfma_f32_16x16x32_bf16(a[mm][0], bb[n][0], acc[qq*2+mm][n], 0,0,0);
        acc[qq*2+mm][n] = __builtin_amdgcn_mfma_f32_16x16x32_bf16(a[mm][1], bb[n][1], acc[qq*2+mm][n], 0,0,0);
      }
    __builtin_amdgcn_s_setprio(0);
  };

  auto ktile = [&](int kt, int ar, int an, int as,
                   v8bf (&bc)[NW][2], v8bf (&bn)[NW][2]){
    char* Ab = sm + ar*32768 + wr*16384;
    char* An = sm + an*32768 + wr*16384;
    char* Bn = sm + BBASE + ((kt+1)&1)*BBUF + wc*(NW*2048);
    const int kAraw = DEEP ? kt+2 : kt+1;
    const int kA = (kAraw < NT ? kAraw : NT-1)*64;
    const int kB = (kt+2 < NT ? kt+2 : NT-1)*64;
    const int db = kt & 1;

    stA(as,0,kA); stA(as,1,kA);
    rdA(af1, Ab, 1);
    FENCE; asm volatile("s_waitcnt lgkmcnt(4)" ::: "memory"); FENCE;
    domfma(af0, bc, 0);
    __builtin_amdgcn_s_barrier();

    stA(as,2,kA); stA(as,3,kA);
    rdA(af0, Ab, 2);
    FENCE; asm volatile("s_waitcnt lgkmcnt(4)" ::: "memory"); FENCE;
    domfma(af1, bc, 1);
    __builtin_amdgcn_s_barrier();

    stB(db,0,kB); stB(db,1,kB);
    rdA(af1, Ab, 3);
    FENCE; asm volatile("s_waitcnt lgkmcnt(4)" ::: "memory"); FENCE;
    domfma(af0, bc, 2);
    if constexpr (DEEP) asm volatile("s_waitcnt vmcnt(6)" ::: "memory");
    else                asm volatile("s_waitcnt vmcnt(2)" ::: "memory");
    __builtin_amdgcn_s_barrier();

    #pragma unroll
    for (int i=2;i<NW;++i) stB(db,i,kB);
    rdA(af0, An, 0);
    rdB(bn, Bn);
    if constexpr (NW==3) { FENCE; asm volatile("s_waitcnt lgkmcnt(10)" ::: "memory"); FENCE; }
    else                 { FENCE; asm volatile("s_waitcnt lgkmcnt(12)" ::: "memory"); FENCE; }
    domfma(af1, bc, 3);
    __builtin_amdgcn_s_barrier();
  };

  #pragma unroll
  for (int i=0;i<4;++i)  stA(0,i,0);
  #pragma unroll
  for (int i=0;i<NW;++i) stB(0,i,0);
  if constexpr (DEEP) {
    #pragma unroll
    for (int i=0;i<4;++i) stA(1,i,64);
  }
  #pragma unroll
  for (int i=0;i<NW;++i) stB(1,i,64);
  if constexpr (DEEP)      asm volatile("s_waitcnt vmcnt(7)" ::: "memory");
  else if constexpr (NW==3) asm volatile("s_waitcnt vmcnt(3)" ::: "memory");
  else                      asm volatile("s_waitcnt vmcnt(4)" ::: "memory");
  __builtin_amdgcn_s_barrier();
  rdB(bX, sm + BBASE + wc*(NW*2048));
  rdA(af0, sm + wr*16384, 0);

  if constexpr (DEEP) {
    int c0 = 0;
    for (int kt = 0; kt < NT; kt += 2) {
      const int c1 = (c0+1==3) ? 0 : c0+1;
      const int c2 = (c1+1==3) ? 0 : c1+1;
      ktile(kt,   c0, c1, c2, bX, bY);
      ktile(kt+1, c1, c2, c0, bY, bX);
      c0 = c2;
    }
  } else {
    for (int kt = 0; kt < NT; kt += 2) {
      ktile(kt,   0, 1, 1, bX, bY);
      ktile(kt+1, 1, 0, 0, bY, bX);
    }
  }
}

// ---------------- convert: x, Wq/Wk/Wv f32 -> bf16 -------------------------
__global__ __launch_bounds__(256) void convert_kernel(
    const float* __restrict__ x,
    const float* __restrict__ Wq, const float* __restrict__ Wk,
    const float* __restrict__ Wv,
    unsigned short* __restrict__ Xb, unsigned short* __restrict__ Wb)
{
  const int NX = 3145728;
  const int NW_ = 147456;
  const int total = NX + 3*NW_;
  for (int i = blockIdx.x*256 + threadIdx.x; i < total; i += gridDim.x*256) {
    const float* src; unsigned short* dst; int off;
    if (i < NX) { src = x; dst = Xb; off = i; }
    else {
      int j = i - NX; int z = j / NW_; off = j - z*NW_;
      src = (z==0) ? Wq : ((z==1) ? Wk : Wv);
      dst = Wb + (size_t)z*589824;
    }
    float4 v = reinterpret_cast<const float4*>(src)[off];
    ushort4 h; h.x=f2b(v.x); h.y=f2b(v.y); h.z=f2b(v.z); h.w=f2b(v.w);
    reinterpret_cast<ushort4*>(dst)[off] = h;
  }
}

// ---------------- QKV: one GEMM [16384x768] x [2304x768]^T, tile 128x192 ---
__global__ __launch_bounds__(512, 4) void qkv_kernel(
    const unsigned short* __restrict__ Xb, const unsigned short* __restrict__ Wb,
    const float* __restrict__ bq, const float* __restrict__ bk,
    const float* __restrict__ bv,
    unsigned short* __restrict__ Qb, unsigned short* __restrict__ Kb,
    unsigned short* __restrict__ Vt)
{
  extern __shared__ unsigned short smem[];
  const int bid = blockIdx.x;                  // 1536 = 8 XCD chunks of 192
  const int wg  = (bid & 7)*192 + (bid >> 3);  // bijective XCD swizzle
  const int mt  = wg / 12, nt = wg % 12;

  f32x4 acc[4][3];
  gemm128(Xb + (size_t)mt*128*768, 768,
          Wb + (size_t)nt*192*768, 768, 12, smem, acc);

  const int tid = threadIdx.x, lane = tid & 63, w = tid >> 6;
  const int wr = w >> 2, wc = w & 3, lr = lane & 15, lg = lane >> 4;
  const int z = nt >> 2;
  const float* bias = (z==0) ? bq : ((z==1) ? bk : bv);
  const int colbase = (nt & 3)*192 + wc*48;

  if (z < 2) {
    unsigned short* dst = (z==0) ? Qb : Kb;
    #pragma unroll
    for (int m=0;m<4;++m){
      int row0 = mt*128 + wr*64 + m*16 + lg*4;
      #pragma unroll
      for (int n=0;n<3;++n){
        int col = colbase + n*16 + lr;
        float bb = bias[col];
        #pragma unroll
        for (int r=0;r<4;++r)
          dst[(size_t)(row0+r)*768 + col] = f2b(acc[m][n][r] + bb);
      }
    }
  } else {
    const int batch = mt >> 3;
    const int ebase = (mt & 7)*128;
    unsigned short* dst = Vt + (size_t)batch*786432;
    #pragma unroll
    for (int m=0;m<4;++m){
      int e0 = ebase + wr*64 + m*16 + lg*4;
      #pragma unroll
      for (int n=0;n<3;++n){
        int col = colbase + n*16 + lr;
        float bb = bias[col];
        ushort4 h;
        h.x = f2b(acc[m][n][0] + bb);
        h.y = f2b(acc[m][n][1] + bb);
        h.z = f2b(acc[m][n][2] + bb);
        h.w = f2b(acc[m][n][3] + bb);
        *reinterpret_cast<ushort4*>(dst + (size_t)col*1024 + e0) = h;
      }
    }
  }
}

// ---------------- scores: E = exp((Q K^T)*768^-0.5), bf16; fused row sums --
// XCD-local: xcd = lid&7 owns batches {2x,2x+1} (Q+K 3MB near its 4MB L2).
// If D != nullptr: per-thread partials -> shfl_xor reduce over lr(16) ->
// atomicAdd(D[row]) from lane lr==0 (16 adds/row total; f32 atomics are
// device-scope, G12/m20). Replaces the 7us rowsum kernel's 32MB re-read.
__global__ __launch_bounds__(512, 2) void scores_kernel(
    const unsigned short* __restrict__ Qb,
    const unsigned short* __restrict__ Kb,
    unsigned short* __restrict__ Eb,
    float* __restrict__ D)
{
  extern __shared__ unsigned short smem[];
  const int lid = blockIdx.x;
  const int seq = lid >> 3;
  const int b   = (lid & 7)*2 + (seq >> 4);
  const int t   = seq & 15;
  const int mt  = t >> 2, nt = t & 3;

  f32x4 acc[8][4];
  gemmcore<4,false>(Qb + (size_t)b*786432 + (size_t)mt*256*768, 768,
                    Kb + (size_t)b*786432 + (size_t)nt*256*768, 768,
                    12, smem, acc);

  const float scale = 0.03608439182435161f; // 768^-0.5
  const int tid = threadIdx.x, lane = tid & 63, w = tid >> 6;
  const int wr = w >> 2, wc = w & 3, lr = lane & 15, lg = lane >> 4;
  unsigned short* dst = Eb + (size_t)b*1048576;
  float* Drow = D ? (D + b*1024) : nullptr;
  #pragma unroll
  for (int m=0;m<8;++m){
    int row0 = mt*256 + wr*128 + m*16 + lg*4;
    float rp0=0.f, rp1=0.f, rp2=0.f, rp3=0.f;
    #pragma unroll
    for (int n=0;n<4;++n){
      int col = nt*256 + wc*64 + n*16 + lr;
      float e0 = __expf(acc[m][n][0] * scale);
      float e1 = __expf(acc[m][n][1] * scale);
      float e2 = __expf(acc[m][n][2] * scale);
      float e3 = __expf(acc[m][n][3] * scale);
      dst[(size_t)(row0+0)*1024 + col] = f2b(e0);
      dst[(size_t)(row0+1)*1024 + col] = f2b(e1);
      dst[(size_t)(row0+2)*1024 + col] = f2b(e2);
      dst[(size_t)(row0+3)*1024 + col] = f2b(e3);
      rp0 += e0; rp1 += e1; rp2 += e2; rp3 += e3;
    }
    if (Drow) {
      #pragma unroll
      for (int off=1; off<16; off<<=1){
        rp0 += __shfl_xor(rp0, off, 64);
        rp1 += __shfl_xor(rp1, off, 64);
        rp2 += __shfl_xor(rp2, off, 64);
        rp3 += __shfl_xor(rp3, off, 64);
      }
      if (lr == 0){
        int rb = row0 & 1023;   // row within batch
        atomicAdd(&Drow[rb+0], rp0);
        atomicAdd(&Drow[rb+1], rp1);
        atomicAdd(&Drow[rb+2], rp2);
        atomicAdd(&Drow[rb+3], rp3);
      }
    }
  }
}

// ---------------- rowsum (fallback only): D[b*1024+c] = sum_e E[b][c][e] ---
__global__ __launch_bounds__(256) void rowsum_kernel(
    const unsigned short* __restrict__ E, float* __restrict__ D)
{
  int row  = blockIdx.x*4 + (threadIdx.x >> 6);
  int lane = threadIdx.x & 63;
  const unsigned short* p = E + (size_t)row*1024 + lane*16;
  uint4 v0 = *reinterpret_cast<const uint4*>(p);
  uint4 v1 = *reinterpret_cast<const uint4*>(p + 8);
  unsigned int uu[8] = {v0.x, v0.y, v0.z, v0.w, v1.x, v1.y, v1.z, v1.w};
  float s = 0.f;
  #pragma unroll
  for (int i=0;i<8;++i){ s += b2f(uu[i] & 0xffffu); s += b2f(uu[i] >> 16); }
  #pragma unroll
  for (int off=1; off<64; off<<=1) s += __shfl_xor(s, off, 64);
  if (lane == 0) D[row] = s;
}

// -------- PV: out[b, n*1024+c] = (E V)[c,n]/D[b,c] + x[b, n*1024+c] --------
__global__ __launch_bounds__(512, 2) void pv_kernel(
    const unsigned short* __restrict__ Eb,
    const unsigned short* __restrict__ Vt,
    const float* __restrict__ D,
    const float* __restrict__ x, float* __restrict__ out)
{
  extern __shared__ unsigned short smem[];
  const int lid = blockIdx.x;
  const int seq = lid >> 3;
  const int b   = (lid & 7)*2 + (seq >> 4);
  const int t   = seq & 15;
  const int mt  = t >> 2, nt = t & 3;

  f32x4 acc[8][3];
  gemmcore<3,true>(Eb + (size_t)b*1048576 + (size_t)mt*256*1024, 1024,
                   Vt + (size_t)b*786432  + (size_t)nt*192*1024, 1024,
                   16, smem, acc);

  const int tid = threadIdx.x, lane = tid & 63, w = tid >> 6;
  const int wr = w >> 2, wc = w & 3, lr = lane & 15, lg = lane >> 4;
  const float* xb = x   + (size_t)b*786432;
  float*       ob = out + (size_t)b*786432;
  const float* Db = D + b*1024;
  #pragma unroll
  for (int m=0;m<8;++m){
    int c0 = mt*256 + wr*128 + m*16 + lg*4;
    float inv0 = 1.0f / Db[c0+0];
    float inv1 = 1.0f / Db[c0+1];
    float inv2 = 1.0f / Db[c0+2];
    float inv3 = 1.0f / Db[c0+3];
    #pragma unroll
    for (int n=0;n<3;++n){
      int col = nt*192 + wc*48 + n*16 + lr;
      size_t idx = (size_t)col*1024 + c0;
      float4 xv = *reinterpret_cast<const float4*>(xb + idx);
      float4 o;
      o.x = acc[m][n][0]*inv0 + xv.x;
      o.y = acc[m][n][1]*inv1 + xv.y;
      o.z = acc[m][n][2]*inv2 + xv.z;
      o.w = acc[m][n][3]*inv3 + xv.w;
      *reinterpret_cast<float4*>(ob + idx) = o;
    }
  }
}

extern "C" void kernel_launch(void* const* d_in, const int* in_sizes, int n_in,
                              void* d_out, int out_size, void* d_ws, size_t ws_size,
                              hipStream_t stream)
{
  const float* x  = (const float*)d_in[0];
  const float* Wq = (const float*)d_in[1];
  const float* bq = (const float*)d_in[2];
  const float* Wk = (const float*)d_in[3];
  const float* bk = (const float*)d_in[4];
  const float* Wv = (const float*)d_in[5];
  const float* bv = (const float*)d_in[6];
  float* out = (float*)d_out;

  // Workspace (aliased):
  //   [0, 32M)   : Xb (24M) + Wb (3.4M) during convert+qkv; Eb (32M) after
  //   [32M, 56M) : Qb   [56M, 80M) : Kb   [80M, 104M) : Vt  (ends 109051904)
  //   D: ws tail (64KB) if ws_size permits (fused rowsum); else dead-Qb alias
  //      + separate rowsum kernel (r10 fallback, proven 144.4us).
  char* ws = (char*)d_ws;
  unsigned short* Xb = (unsigned short*)(ws);
  unsigned short* Wb = (unsigned short*)(ws + 25165824);
  unsigned short* Eb = (unsigned short*)(ws);
  unsigned short* Qb = (unsigned short*)(ws + 33554432);
  unsigned short* Kb = (unsigned short*)(ws + 58720256);
  unsigned short* Vt = (unsigned short*)(ws + 83886080);

  const bool fused = ws_size >= (size_t)109051904 + 65536;
  float* Dd = fused ? (float*)(ws + 109051904)
                    : (float*)(ws + 33554432);   // dead-Qb alias (post-scores)

  convert_kernel<<<dim3(2048), dim3(256), 0,      stream>>>(x, Wq, Wk, Wv, Xb, Wb);
  qkv_kernel    <<<dim3(1536), dim3(512), 81920,  stream>>>(Xb, Wb, bq, bk, bv, Qb, Kb, Vt);
  if (fused) {
    hipMemsetAsync(Dd, 0, 16384*sizeof(float), stream);
    scores_kernel <<<dim3(256),  dim3(512), 131072, stream>>>(Qb, Kb, Eb, Dd);
  } else {
    scores_kernel <<<dim3(256),  dim3(512), 131072, stream>>>(Qb, Kb, Eb, nullptr);
    rowsum_kernel <<<dim3(4096), dim3(256), 0,      stream>>>(Eb, Dd);
  }
  pv_kernel     <<<dim3(256),  dim3(512), 147456, stream>>>(Eb, Vt, Dd, x, out);
}